// Round 8
// baseline (416.115 us; speedup 1.0000x reference)
//
#include <hip/hip_runtime.h>
#include <math.h>

typedef short short8 __attribute__((ext_vector_type(8)));
typedef float f32x4 __attribute__((ext_vector_type(4)));

#define B_ 16
#define TQ_ 64
#define TK_ 512
#define D_ 256
#define V_ 32000
#define M_ (B_ * TQ_)   // 1024 rows

__device__ __forceinline__ unsigned short f2bf(float x) {
    unsigned int u = __float_as_uint(x);
    unsigned int r = (u + 0x7fffu + ((u >> 16) & 1u)) >> 16;
    return (unsigned short)r;
}

__device__ __forceinline__ void gload_lds16(const void* g, void* l) {
    __builtin_amdgcn_global_load_lds(
        (const __attribute__((address_space(1))) void*)g,
        (__attribute__((address_space(3))) void*)l, 16, 0, 0);
}

// ---------------- fused prep: dedup | conv_w | conv_c | conv_a | zero-Z ----------------
// blocks [0,16): dedup; [16,2016): W transpose+bf16; [2016,2528): context bf16+transpose;
// [2528,2784): out_states bf16; [2784]: zero Z (replaces hipMemsetAsync launch).
__global__ __launch_bounds__(256) void prep_kernel(
    const float* __restrict__ W, unsigned short* __restrict__ Wt,
    const float* __restrict__ ctx, unsigned short* __restrict__ Cb,
    unsigned short* __restrict__ Ct,
    const float* __restrict__ A, unsigned short* __restrict__ Ab,
    const int* __restrict__ cp, int* __restrict__ nexta, int* __restrict__ leader,
    float* __restrict__ Z)
{
    __shared__ float tile[64][65];
    __shared__ __align__(16) int c[TK_];
    const int bid = blockIdx.x;
    const int tid = threadIdx.x;

    if (bid < 16) {                         // ---- dedup ----
        const int b = bid;
        c[tid] = cp[b * TK_ + tid];
        c[tid + 256] = cp[b * TK_ + 256 + tid];
        __syncthreads();
        for (int k = tid; k < TK_; k += 256) {
            const int v = c[k];
            int fm = 1024, nx = 1024;
#pragma unroll 8
            for (int j0 = 0; j0 < TK_; j0 += 4) {
                const int4 q = *(const int4*)&c[j0];
                if (q.x == v) { fm = min(fm, j0);     if (j0     > k) nx = min(nx, j0);     }
                if (q.y == v) { fm = min(fm, j0 + 1); if (j0 + 1 > k) nx = min(nx, j0 + 1); }
                if (q.z == v) { fm = min(fm, j0 + 2); if (j0 + 2 > k) nx = min(nx, j0 + 2); }
                if (q.w == v) { fm = min(fm, j0 + 3); if (j0 + 3 > k) nx = min(nx, j0 + 3); }
            }
            nexta[b * TK_ + k] = (nx < 1024) ? nx : -1;
            leader[b * TK_ + k] = (fm == k) ? 1 : 0;
        }
    } else if (bid < 2016) {                // ---- conv_w ----
        const int wb = bid - 16;
        const int k0 = (wb & 3) * 64;
        const int n0 = (wb >> 2) * 64;
#pragma unroll
        for (int i = 0; i < 16; i++) {
            const int r = i * 4 + (tid >> 6), cc = tid & 63;
            tile[r][cc] = W[(k0 + r) * V_ + n0 + cc];
        }
        __syncthreads();
#pragma unroll
        for (int i = 0; i < 4; i++) {
            const int nl = i * 16 + (tid >> 4);
            const int kq = (tid & 15) * 4;
            ushort4 o;
            o.x = f2bf(tile[kq + 0][nl]);
            o.y = f2bf(tile[kq + 1][nl]);
            o.z = f2bf(tile[kq + 2][nl]);
            o.w = f2bf(tile[kq + 3][nl]);
            *(ushort4*)&Wt[(n0 + nl) * D_ + k0 + kq] = o;
        }
    } else if (bid < 2528) {                // ---- conv_c ----
        const int cbid = bid - 2016;
        const int b = cbid >> 5;
        const int r5 = cbid & 31;
        const int k0 = (r5 >> 2) * 64;
        const int d0 = (r5 & 3) * 64;
#pragma unroll
        for (int i = 0; i < 16; i++) {
            const int r = i * 4 + (tid >> 6), cc = tid & 63;
            const float v = ctx[((b * TK_) + k0 + r) * D_ + d0 + cc];
            tile[r][cc] = v;
            Cb[((b * TK_) + k0 + r) * D_ + d0 + cc] = f2bf(v);
        }
        __syncthreads();
#pragma unroll
        for (int i = 0; i < 4; i++) {
            const int dl = i * 16 + (tid >> 4);
            const int kq = (tid & 15) * 4;
            ushort4 o;
            o.x = f2bf(tile[kq + 0][dl]);
            o.y = f2bf(tile[kq + 1][dl]);
            o.z = f2bf(tile[kq + 2][dl]);
            o.w = f2bf(tile[kq + 3][dl]);
            *(ushort4*)&Ct[((b * D_) + d0 + dl) * TK_ + k0 + kq] = o;
        }
    } else if (bid < 2784) {                // ---- conv_a ----
        const int i = ((bid - 2528) * 256 + tid) * 4;
        const float4 v = *(const float4*)&A[i];
        ushort4 o;
        o.x = f2bf(v.x); o.y = f2bf(v.y); o.z = f2bf(v.z); o.w = f2bf(v.w);
        *(ushort4*)&Ab[i] = o;
    } else {                                // ---- zero Z ----
        ((float4*)Z)[tid] = float4{0.f, 0.f, 0.f, 0.f};
    }
}

// ---------------- small batched GEMM: C[b] = A[b] @ Bt[b]^T (both bf16, K-contiguous) ----
template <int LDA, int LDB, int KTOT>
__global__ __launch_bounds__(256) void gemm_small(
    const unsigned short* __restrict__ A,
    const unsigned short* __restrict__ Bt,
    float* __restrict__ C, int ldc, int nchunks, int btrows, float scale)
{
    __shared__ short Al[64][72];
    __shared__ short Bl[128][72];
    const int tid = threadIdx.x;
    const int b = blockIdx.x / nchunks;
    const int n0 = (blockIdx.x % nchunks) * 128;
    A += (size_t)b * 64 * LDA;
    Bt += (size_t)b * btrows * LDB;
    C += (size_t)b * 64 * ldc;

    const int wid = tid >> 6;
    const int lane = tid & 63;
    const int wm = wid & 1, wn = wid >> 1;
    const int quad = lane >> 4, l15 = lane & 15;

    f32x4 acc[2][4];
#pragma unroll
    for (int i = 0; i < 2; i++)
#pragma unroll
        for (int j = 0; j < 4; j++) acc[i][j] = f32x4{0.f, 0.f, 0.f, 0.f};

    for (int k0 = 0; k0 < KTOT; k0 += 64) {
        __syncthreads();
#pragma unroll
        for (int i = 0; i < 2; i++) {
            const int c = tid + i * 256;
            const int r = c >> 3, kc = (c & 7) * 8;
            *(uint4*)&Al[r][kc] = *(const uint4*)&A[r * LDA + k0 + kc];
        }
#pragma unroll
        for (int i = 0; i < 4; i++) {
            const int c = tid + i * 256;
            const int r = c >> 3, kc = (c & 7) * 8;
            *(uint4*)&Bl[r][kc] = *(const uint4*)&Bt[(n0 + r) * LDB + k0 + kc];
        }
        __syncthreads();
#pragma unroll
        for (int ks = 0; ks < 64; ks += 32) {
            short8 af[2], bf[4];
#pragma unroll
            for (int mt = 0; mt < 2; mt++)
                af[mt] = *(const short8*)&Al[wm * 32 + mt * 16 + l15][ks + quad * 8];
#pragma unroll
            for (int nt = 0; nt < 4; nt++)
                bf[nt] = *(const short8*)&Bl[wn * 64 + nt * 16 + l15][ks + quad * 8];
#pragma unroll
            for (int mt = 0; mt < 2; mt++)
#pragma unroll
                for (int nt = 0; nt < 4; nt++)
                    acc[mt][nt] = __builtin_amdgcn_mfma_f32_16x16x32_bf16(
                        af[mt], bf[nt], acc[mt][nt], 0, 0, 0);
        }
    }
#pragma unroll
    for (int mt = 0; mt < 2; mt++)
#pragma unroll
        for (int nt = 0; nt < 4; nt++)
#pragma unroll
            for (int r = 0; r < 4; r++) {
                const int rl = wm * 32 + mt * 16 + quad * 4 + r;
                const int col = n0 + wn * 64 + nt * 16 + l15;
                C[rl * ldc + col] = acc[mt][nt][r] * scale;
            }
}

// ---------------- softmax over S rows; write attn f32 in-place + P bf16 ----------------
__global__ __launch_bounds__(256) void softmax_kernel(
    float* __restrict__ S, unsigned short* __restrict__ Pb)
{
    const int w = threadIdx.x >> 6, lane = threadIdx.x & 63;
    const int row = blockIdx.x * 4 + w;
    float v[8], m = -1e30f;
#pragma unroll
    for (int j = 0; j < 8; j++) { v[j] = S[row * TK_ + lane + 64 * j]; m = fmaxf(m, v[j]); }
#pragma unroll
    for (int off = 32; off; off >>= 1) m = fmaxf(m, __shfl_xor(m, off));
    float s = 0.f;
#pragma unroll
    for (int j = 0; j < 8; j++) { v[j] = __expf(v[j] - m); s += v[j]; }
#pragma unroll
    for (int off = 32; off; off >>= 1) s += __shfl_xor(s, off);
    const float inv = 1.0f / s;
#pragma unroll
    for (int j = 0; j < 8; j++) {
        const float p = v[j] * inv;
        S[row * TK_ + lane + 64 * j] = p;
        Pb[row * TK_ + lane + 64 * j] = f2bf(p);
    }
}

// ---------------- p_gen: sigmoid(os.wg0 + cv.wg1 + dm.wg2 + b) per row ----------------
__global__ __launch_bounds__(256) void pgen_kernel(
    const float* __restrict__ os, const float* __restrict__ cv,
    const float* __restrict__ dm, const float* __restrict__ W_gen,
    const float* __restrict__ b_gen, float* __restrict__ pg)
{
    const int w = threadIdx.x >> 6, lane = threadIdx.x & 63;
    const int row = blockIdx.x * 4 + w;
    const int d4 = lane * 4;
    const float4 o4 = *(const float4*)&os[row * D_ + d4];
    const float4 c4 = *(const float4*)&cv[row * D_ + d4];
    const float4 m4 = *(const float4*)&dm[row * D_ + d4];
    const float4 w0 = *(const float4*)&W_gen[d4];
    const float4 w1 = *(const float4*)&W_gen[D_ + d4];
    const float4 w2 = *(const float4*)&W_gen[2 * D_ + d4];
    float p = o4.x * w0.x + o4.y * w0.y + o4.z * w0.z + o4.w * w0.w
            + c4.x * w1.x + c4.y * w1.y + c4.z * w1.z + c4.w * w1.w
            + m4.x * w2.x + m4.y * w2.y + m4.z * w2.z + m4.w * w2.w;
#pragma unroll
    for (int off = 32; off; off >>= 1) p += __shfl_xor(p, off);
    if (lane == 0) pg[row] = 1.0f / (1.0f + __expf(-(p + b_gen[0])));
}

// ---------------- vocab GEMM pass 1: Z[row] += sum(exp(logit)) — NO logit store --------
// R3 structure: BK=64, 32KB LDS, multi-block overlap + T2 swizzle (rule #21:
// linear LDS dest, pre-swizzled global source column, swizzled ds_read).
__global__ __launch_bounds__(256) void gemm_vocab_z(
    const unsigned short* __restrict__ A,   // [1024][256] bf16
    const unsigned short* __restrict__ Bt,  // [32000][256] bf16
    const float* __restrict__ b_state,
    float* __restrict__ Z)
{
    __shared__ short Al[128][64];   // 16 KB
    __shared__ short Bl[128][64];   // 16 KB
    __shared__ float bst[128];

    const int tid = threadIdx.x;
    const int swz = (blockIdx.x & 7) * 250 + (blockIdx.x >> 3);  // bijective XCD swizzle
    const int m0 = (swz & 7) * 128;     // m-major: consecutive swz share Wt n-tile
    const int n0 = (swz >> 3) * 128;

    if (tid < 128) bst[tid] = b_state[n0 + tid];

    const int wid = tid >> 6, lane = tid & 63;
    const int wm = wid & 1, wn = wid >> 1;
    const int quad = lane >> 4, l15 = lane & 15;
    const int srow = lane >> 3;                        // row within 8-row chunk (=r&7)
    const int scolz = ((lane & 7) ^ srow) << 3;        // pre-swizzled source column

    f32x4 acc[4][4];
#pragma unroll
    for (int i = 0; i < 4; i++)
#pragma unroll
        for (int j = 0; j < 4; j++) acc[i][j] = f32x4{0.f, 0.f, 0.f, 0.f};

    for (int k0 = 0; k0 < D_; k0 += 64) {
        __syncthreads();
#pragma unroll
        for (int j = 0; j < 4; j++) {
            const int c = j * 4 + wid;
            const int r = c * 8 + srow;
            gload_lds16(&A[(size_t)(m0 + r) * D_ + k0 + scolz], &Al[c * 8][0]);
        }
#pragma unroll
        for (int j = 0; j < 4; j++) {
            const int c = j * 4 + wid;
            const int r = c * 8 + srow;
            gload_lds16(&Bt[(size_t)(n0 + r) * D_ + k0 + scolz], &Bl[c * 8][0]);
        }
        __syncthreads();
#pragma unroll
        for (int ks = 0; ks < 64; ks += 32) {
            short8 af[4], bf[4];
#pragma unroll
            for (int mt = 0; mt < 4; mt++) {
                const int row = wm * 64 + mt * 16 + l15;
                af[mt] = *(const short8*)&Al[row][(ks + quad * 8) ^ ((l15 & 7) << 3)];
            }
#pragma unroll
            for (int nt = 0; nt < 4; nt++) {
                const int row = wn * 64 + nt * 16 + l15;
                bf[nt] = *(const short8*)&Bl[row][(ks + quad * 8) ^ ((l15 & 7) << 3)];
            }
#pragma unroll
            for (int mt = 0; mt < 4; mt++)
#pragma unroll
                for (int nt = 0; nt < 4; nt++)
                    acc[mt][nt] = __builtin_amdgcn_mfma_f32_16x16x32_bf16(
                        af[mt], bf[nt], acc[mt][nt], 0, 0, 0);
        }
    }

#pragma unroll
    for (int mt = 0; mt < 4; mt++) {
        float rs[4] = {0.f, 0.f, 0.f, 0.f};
#pragma unroll
        for (int nt = 0; nt < 4; nt++) {
            const float bcol = bst[wn * 64 + nt * 16 + l15];
#pragma unroll
            for (int r = 0; r < 4; r++)
                rs[r] += __expf(acc[mt][nt][r] + bcol);
        }
#pragma unroll
        for (int r = 0; r < 4; r++) {
            float v = rs[r];
            v += __shfl_xor(v, 1);
            v += __shfl_xor(v, 2);
            v += __shfl_xor(v, 4);
            v += __shfl_xor(v, 8);
            if (l15 == 0)
                atomicAdd(&Z[m0 + wm * 64 + mt * 16 + quad * 4 + r], v);
        }
    }
}

// ---------------- vocab GEMM pass 2 + fused sparse fixup ----------------
// out = logit + bias + log(pg)-log(Z). Then: every fixup target (row, v) lies in
// exactly one block's tile (v in one 128-col range; each batch's 64 rows in one
// 128-row m-block). Preamble scans the 2 batches' leader flags for v in [n0,n0+128)
// (~4 matches/block expected); after the plain stores, owning lanes recompute the
// final value from live acc registers and re-store log(exp(v0) + (1-pg)*chain_sum).
// Arithmetic verbatim from the old fixup_kernel -> bit-identical output.
__global__ __launch_bounds__(256) void gemm_vocab_out(
    const unsigned short* __restrict__ A,   // [1024][256] bf16
    const unsigned short* __restrict__ Bt,  // [32000][256] bf16
    const float* __restrict__ b_state,
    const float* __restrict__ pg,
    const float* __restrict__ Z,
    const int* __restrict__ cp,
    const int* __restrict__ nexta,
    const int* __restrict__ leader,
    const float* __restrict__ S,            // attn probs [1024][512]
    float* __restrict__ out)
{
    __shared__ short Al[128][64];   // 16 KB
    __shared__ short Bl[128][64];   // 16 KB
    __shared__ float bst[128];
    __shared__ float rcs[128];
    __shared__ int mlist[256];      // packed matches: (h<<16)|(k<<7)|col_local
    __shared__ int nm_sh;

    const int tid = threadIdx.x;
    const int swz = (blockIdx.x & 7) * 250 + (blockIdx.x >> 3);  // bijective XCD swizzle
    const int m0 = (swz & 7) * 128;
    const int n0 = (swz >> 3) * 128;

    if (tid < 128) {
        bst[tid] = b_state[n0 + tid];
        rcs[tid] = logf(pg[m0 + tid]) - logf(Z[m0 + tid]);
    }
    if (tid == 0) nm_sh = 0;
    __syncthreads();
    // scan leaders of the block's 2 batches for values in this n-range
#pragma unroll
    for (int h = 0; h < 2; h++) {
        const int b = (m0 >> 6) + h;
        for (int k = tid; k < TK_; k += 256) {
            if (leader[b * TK_ + k]) {
                const int v = cp[b * TK_ + k];
                if (v >= n0 && v < n0 + 128) {
                    const int e = atomicAdd(&nm_sh, 1);
                    if (e < 256) mlist[e] = (h << 16) | (k << 7) | (v - n0);
                }
            }
        }
    }
    // (k-loop barriers below make mlist/nm_sh visible before the epilogue)

    const int wid = tid >> 6, lane = tid & 63;
    const int wm = wid & 1, wn = wid >> 1;
    const int quad = lane >> 4, l15 = lane & 15;
    const int srow = lane >> 3;
    const int scolz = ((lane & 7) ^ srow) << 3;        // pre-swizzled source column

    f32x4 acc[4][4];
#pragma unroll
    for (int i = 0; i < 4; i++)
#pragma unroll
        for (int j = 0; j < 4; j++) acc[i][j] = f32x4{0.f, 0.f, 0.f, 0.f};

    for (int k0 = 0; k0 < D_; k0 += 64) {
        __syncthreads();
#pragma unroll
        for (int j = 0; j < 4; j++) {
            const int c = j * 4 + wid;
            const int r = c * 8 + srow;
            gload_lds16(&A[(size_t)(m0 + r) * D_ + k0 + scolz], &Al[c * 8][0]);
        }
#pragma unroll
        for (int j = 0; j < 4; j++) {
            const int c = j * 4 + wid;
            const int r = c * 8 + srow;
            gload_lds16(&Bt[(size_t)(n0 + r) * D_ + k0 + scolz], &Bl[c * 8][0]);
        }
        __syncthreads();
#pragma unroll
        for (int ks = 0; ks < 64; ks += 32) {
            short8 af[4], bf[4];
#pragma unroll
            for (int mt = 0; mt < 4; mt++) {
                const int row = wm * 64 + mt * 16 + l15;
                af[mt] = *(const short8*)&Al[row][(ks + quad * 8) ^ ((l15 & 7) << 3)];
            }
#pragma unroll
            for (int nt = 0; nt < 4; nt++) {
                const int row = wn * 64 + nt * 16 + l15;
                bf[nt] = *(const short8*)&Bl[row][(ks + quad * 8) ^ ((l15 & 7) << 3)];
            }
#pragma unroll
            for (int mt = 0; mt < 4; mt++)
#pragma unroll
                for (int nt = 0; nt < 4; nt++)
                    acc[mt][nt] = __builtin_amdgcn_mfma_f32_16x16x32_bf16(
                        af[mt], bf[nt], acc[mt][nt], 0, 0, 0);
        }
    }

    // plain stores (branch-free hot path)
#pragma unroll
    for (int mt = 0; mt < 4; mt++) {
#pragma unroll
        for (int nt = 0; nt < 4; nt++) {
            const float bcol = bst[wn * 64 + nt * 16 + l15];
#pragma unroll
            for (int r = 0; r < 4; r++) {
                const int row = wm * 64 + mt * 16 + quad * 4 + r;
                const int col = wn * 64 + nt * 16 + l15;
                out[(size_t)(m0 + row) * V_ + n0 + col] = acc[mt][nt][r] + bcol + rcs[row];
            }
        }
    }

    // sparse fixup: re-store corrected values for matched columns (rare)
    const int nm = (nm_sh < 256) ? nm_sh : 256;
    for (int e = 0; e < nm; e++) {
        const int pk = mlist[e];
        const int cl = pk & 127;            // col local 0..127
        const int h  = (pk >> 16) & 1;      // batch half = required wm
        if ((cl >> 6) == wn && (cl & 15) == l15 && h == wm) {
            const int nt = (cl >> 4) & 3;
            const int k  = (pk >> 7) & 511;
            const int b  = (m0 >> 6) + h;
#pragma unroll
            for (int mt = 0; mt < 4; mt++)
#pragma unroll
                for (int r = 0; r < 4; r++) {
                    const int row = wm * 64 + mt * 16 + quad * 4 + r;
                    const int rr = m0 + row;
                    float a = S[(size_t)rr * TK_ + k];
                    int j = nexta[b * TK_ + k];
                    while (j >= 0) { a += S[(size_t)rr * TK_ + j]; j = nexta[b * TK_ + j]; }
                    const float v0 = acc[mt][nt][r] + bst[cl] + rcs[row];
                    out[(size_t)rr * V_ + n0 + cl] =
                        logf(expf(v0) + (1.0f - pg[rr]) * a);
                }
        }
    }
}

extern "C" void kernel_launch(void* const* d_in, const int* in_sizes, int n_in,
                              void* d_out, int out_size, void* d_ws, size_t ws_size,
                              hipStream_t stream)
{
    const float* domainslots = (const float*)d_in[0];
    const float* out_states  = (const float*)d_in[1];
    const float* context     = (const float*)d_in[2];
    const int*   cp          = (const int*)d_in[3];
    const float* W_state     = (const float*)d_in[4];
    const float* b_state     = (const float*)d_in[5];
    const float* W_gen       = (const float*)d_in[6];
    const float* b_gen       = (const float*)d_in[7];
    float* out = (float*)d_out;
    char* ws = (char*)d_ws;

    // workspace layout (bytes)
    float* Z      = (float*)(ws);                          //  4 KB
    float* pg     = (float*)(ws + 4096);                   //  4 KB
    float* S      = (float*)(ws + 12288);                  //  2 MB (scores -> attn in place)
    int* nexta    = (int*)(ws + 2109440);                  // 32 KB
    int* leader   = (int*)(ws + 2142208);                  // 32 KB
    unsigned short* Ab = (unsigned short*)(ws + 2174976);  // 512 KB
    unsigned short* Wt = (unsigned short*)(ws + 2699264);  // 16 MB -> ends 19083264
    unsigned short* Cb = (unsigned short*)(ws + 19083264); // 4 MB
    unsigned short* Ct = (unsigned short*)(ws + 23277568); // 4 MB
    unsigned short* Pb = (unsigned short*)(ws + 27471872); // 1 MB
    float* cv     = (float*)(ws + 28520448);               // 1 MB -> ends ~29.6 MB

    // L1: fused prep (dedup + conv_w + conv_c + conv_a + zero-Z)
    prep_kernel<<<2785, 256, 0, stream>>>(W_state, Wt, context, Cb, Ct,
                                          out_states, Ab, cp, nexta, leader, Z);

    // L2: QK — S = Ab @ Cb^T / 16 : per batch M=64,N=512,K=256
    gemm_small<D_, D_, D_><<<B_ * 4, 256, 0, stream>>>(Ab, Cb, S, TK_, 4, TK_, 0.0625f);

    // L3: softmax
    softmax_kernel<<<M_ / 4, 256, 0, stream>>>(S, Pb);

    // L4: PV — cv = P @ C : per batch M=64,N=256,K=512 (Bt = Ct)
    gemm_small<TK_, TK_, TK_><<<B_ * 2, 256, 0, stream>>>(Pb, Ct, cv, D_, 2, D_, 1.0f);

    // L5: pgen
    pgen_kernel<<<M_ / 4, 256, 0, stream>>>(out_states, cv, domainslots, W_gen, b_gen, pg);

    // L6: vocab pass 1 — Z only
    gemm_vocab_z<<<(M_ / 128) * (V_ / 128), 256, 0, stream>>>(Ab, Wt, b_state, Z);

    // L7: vocab pass 2 + fused fixup — final out
    gemm_vocab_out<<<(M_ / 128) * (V_ / 128), 256, 0, stream>>>(
        Ab, Wt, b_state, pg, Z, cp, nexta, leader, S, out);
}

// Round 9
// 345.294 us; speedup vs baseline: 1.2051x; 1.2051x over previous
//
#include <hip/hip_runtime.h>
#include <math.h>

typedef short short8 __attribute__((ext_vector_type(8)));
typedef float f32x4 __attribute__((ext_vector_type(4)));

#define B_ 16
#define TQ_ 64
#define TK_ 512
#define D_ 256
#define V_ 32000
#define M_ (B_ * TQ_)   // 1024 rows

__device__ __forceinline__ unsigned short f2bf(float x) {
    unsigned int u = __float_as_uint(x);
    unsigned int r = (u + 0x7fffu + ((u >> 16) & 1u)) >> 16;
    return (unsigned short)r;
}

__device__ __forceinline__ void gload_lds16(const void* g, void* l) {
    __builtin_amdgcn_global_load_lds(
        (const __attribute__((address_space(1))) void*)g,
        (__attribute__((address_space(3))) void*)l, 16, 0, 0);
}

// ---------------- fused prep: dedup | conv_w | conv_c | conv_a | zero-Z ----------------
__global__ __launch_bounds__(256) void prep_kernel(
    const float* __restrict__ W, unsigned short* __restrict__ Wt,
    const float* __restrict__ ctx, unsigned short* __restrict__ Cb,
    unsigned short* __restrict__ Ct,
    const float* __restrict__ A, unsigned short* __restrict__ Ab,
    const int* __restrict__ cp, int* __restrict__ nexta, int* __restrict__ leader,
    float* __restrict__ Z)
{
    __shared__ float tile[64][65];
    __shared__ __align__(16) int c[TK_];
    const int bid = blockIdx.x;
    const int tid = threadIdx.x;

    if (bid < 16) {                         // ---- dedup ----
        const int b = bid;
        c[tid] = cp[b * TK_ + tid];
        c[tid + 256] = cp[b * TK_ + 256 + tid];
        __syncthreads();
        for (int k = tid; k < TK_; k += 256) {
            const int v = c[k];
            int fm = 1024, nx = 1024;
#pragma unroll 8
            for (int j0 = 0; j0 < TK_; j0 += 4) {
                const int4 q = *(const int4*)&c[j0];
                if (q.x == v) { fm = min(fm, j0);     if (j0     > k) nx = min(nx, j0);     }
                if (q.y == v) { fm = min(fm, j0 + 1); if (j0 + 1 > k) nx = min(nx, j0 + 1); }
                if (q.z == v) { fm = min(fm, j0 + 2); if (j0 + 2 > k) nx = min(nx, j0 + 2); }
                if (q.w == v) { fm = min(fm, j0 + 3); if (j0 + 3 > k) nx = min(nx, j0 + 3); }
            }
            nexta[b * TK_ + k] = (nx < 1024) ? nx : -1;
            leader[b * TK_ + k] = (fm == k) ? 1 : 0;
        }
    } else if (bid < 2016) {                // ---- conv_w ----
        const int wb = bid - 16;
        const int k0 = (wb & 3) * 64;
        const int n0 = (wb >> 2) * 64;
#pragma unroll
        for (int i = 0; i < 16; i++) {
            const int r = i * 4 + (tid >> 6), cc = tid & 63;
            tile[r][cc] = W[(k0 + r) * V_ + n0 + cc];
        }
        __syncthreads();
#pragma unroll
        for (int i = 0; i < 4; i++) {
            const int nl = i * 16 + (tid >> 4);
            const int kq = (tid & 15) * 4;
            ushort4 o;
            o.x = f2bf(tile[kq + 0][nl]);
            o.y = f2bf(tile[kq + 1][nl]);
            o.z = f2bf(tile[kq + 2][nl]);
            o.w = f2bf(tile[kq + 3][nl]);
            *(ushort4*)&Wt[(n0 + nl) * D_ + k0 + kq] = o;
        }
    } else if (bid < 2528) {                // ---- conv_c ----
        const int cbid = bid - 2016;
        const int b = cbid >> 5;
        const int r5 = cbid & 31;
        const int k0 = (r5 >> 2) * 64;
        const int d0 = (r5 & 3) * 64;
#pragma unroll
        for (int i = 0; i < 16; i++) {
            const int r = i * 4 + (tid >> 6), cc = tid & 63;
            const float v = ctx[((b * TK_) + k0 + r) * D_ + d0 + cc];
            tile[r][cc] = v;
            Cb[((b * TK_) + k0 + r) * D_ + d0 + cc] = f2bf(v);
        }
        __syncthreads();
#pragma unroll
        for (int i = 0; i < 4; i++) {
            const int dl = i * 16 + (tid >> 4);
            const int kq = (tid & 15) * 4;
            ushort4 o;
            o.x = f2bf(tile[kq + 0][dl]);
            o.y = f2bf(tile[kq + 1][dl]);
            o.z = f2bf(tile[kq + 2][dl]);
            o.w = f2bf(tile[kq + 3][dl]);
            *(ushort4*)&Ct[((b * D_) + d0 + dl) * TK_ + k0 + kq] = o;
        }
    } else if (bid < 2784) {                // ---- conv_a ----
        const int i = ((bid - 2528) * 256 + tid) * 4;
        const float4 v = *(const float4*)&A[i];
        ushort4 o;
        o.x = f2bf(v.x); o.y = f2bf(v.y); o.z = f2bf(v.z); o.w = f2bf(v.w);
        *(ushort4*)&Ab[i] = o;
    } else {                                // ---- zero Z ----
        ((float4*)Z)[tid] = float4{0.f, 0.f, 0.f, 0.f};
    }
}

// ---------------- small batched GEMM: C[b] = A[b] @ Bt[b]^T (both bf16, K-contiguous) ----
template <int LDA, int LDB, int KTOT>
__global__ __launch_bounds__(256) void gemm_small(
    const unsigned short* __restrict__ A,
    const unsigned short* __restrict__ Bt,
    float* __restrict__ C, int ldc, int nchunks, int btrows, float scale)
{
    __shared__ short Al[64][72];
    __shared__ short Bl[128][72];
    const int tid = threadIdx.x;
    const int b = blockIdx.x / nchunks;
    const int n0 = (blockIdx.x % nchunks) * 128;
    A += (size_t)b * 64 * LDA;
    Bt += (size_t)b * btrows * LDB;
    C += (size_t)b * 64 * ldc;

    const int wid = tid >> 6;
    const int lane = tid & 63;
    const int wm = wid & 1, wn = wid >> 1;
    const int quad = lane >> 4, l15 = lane & 15;

    f32x4 acc[2][4];
#pragma unroll
    for (int i = 0; i < 2; i++)
#pragma unroll
        for (int j = 0; j < 4; j++) acc[i][j] = f32x4{0.f, 0.f, 0.f, 0.f};

    for (int k0 = 0; k0 < KTOT; k0 += 64) {
        __syncthreads();
#pragma unroll
        for (int i = 0; i < 2; i++) {
            const int c = tid + i * 256;
            const int r = c >> 3, kc = (c & 7) * 8;
            *(uint4*)&Al[r][kc] = *(const uint4*)&A[r * LDA + k0 + kc];
        }
#pragma unroll
        for (int i = 0; i < 4; i++) {
            const int c = tid + i * 256;
            const int r = c >> 3, kc = (c & 7) * 8;
            *(uint4*)&Bl[r][kc] = *(const uint4*)&Bt[(n0 + r) * LDB + k0 + kc];
        }
        __syncthreads();
#pragma unroll
        for (int ks = 0; ks < 64; ks += 32) {
            short8 af[2], bf[4];
#pragma unroll
            for (int mt = 0; mt < 2; mt++)
                af[mt] = *(const short8*)&Al[wm * 32 + mt * 16 + l15][ks + quad * 8];
#pragma unroll
            for (int nt = 0; nt < 4; nt++)
                bf[nt] = *(const short8*)&Bl[wn * 64 + nt * 16 + l15][ks + quad * 8];
#pragma unroll
            for (int mt = 0; mt < 2; mt++)
#pragma unroll
                for (int nt = 0; nt < 4; nt++)
                    acc[mt][nt] = __builtin_amdgcn_mfma_f32_16x16x32_bf16(
                        af[mt], bf[nt], acc[mt][nt], 0, 0, 0);
        }
    }
#pragma unroll
    for (int mt = 0; mt < 2; mt++)
#pragma unroll
        for (int nt = 0; nt < 4; nt++)
#pragma unroll
            for (int r = 0; r < 4; r++) {
                const int rl = wm * 32 + mt * 16 + quad * 4 + r;
                const int col = n0 + wn * 64 + nt * 16 + l15;
                C[rl * ldc + col] = acc[mt][nt][r] * scale;
            }
}

// ---------------- softmax over S rows; write attn f32 in-place + P bf16 ----------------
__global__ __launch_bounds__(256) void softmax_kernel(
    float* __restrict__ S, unsigned short* __restrict__ Pb)
{
    const int w = threadIdx.x >> 6, lane = threadIdx.x & 63;
    const int row = blockIdx.x * 4 + w;
    float v[8], m = -1e30f;
#pragma unroll
    for (int j = 0; j < 8; j++) { v[j] = S[row * TK_ + lane + 64 * j]; m = fmaxf(m, v[j]); }
#pragma unroll
    for (int off = 32; off; off >>= 1) m = fmaxf(m, __shfl_xor(m, off));
    float s = 0.f;
#pragma unroll
    for (int j = 0; j < 8; j++) { v[j] = __expf(v[j] - m); s += v[j]; }
#pragma unroll
    for (int off = 32; off; off >>= 1) s += __shfl_xor(s, off);
    const float inv = 1.0f / s;
#pragma unroll
    for (int j = 0; j < 8; j++) {
        const float p = v[j] * inv;
        S[row * TK_ + lane + 64 * j] = p;
        Pb[row * TK_ + lane + 64 * j] = f2bf(p);
    }
}

// ---------------- p_gen: sigmoid(os.wg0 + cv.wg1 + dm.wg2 + b) per row ----------------
__global__ __launch_bounds__(256) void pgen_kernel(
    const float* __restrict__ os, const float* __restrict__ cv,
    const float* __restrict__ dm, const float* __restrict__ W_gen,
    const float* __restrict__ b_gen, float* __restrict__ pg)
{
    const int w = threadIdx.x >> 6, lane = threadIdx.x & 63;
    const int row = blockIdx.x * 4 + w;
    const int d4 = lane * 4;
    const float4 o4 = *(const float4*)&os[row * D_ + d4];
    const float4 c4 = *(const float4*)&cv[row * D_ + d4];
    const float4 m4 = *(const float4*)&dm[row * D_ + d4];
    const float4 w0 = *(const float4*)&W_gen[d4];
    const float4 w1 = *(const float4*)&W_gen[D_ + d4];
    const float4 w2 = *(const float4*)&W_gen[2 * D_ + d4];
    float p = o4.x * w0.x + o4.y * w0.y + o4.z * w0.z + o4.w * w0.w
            + c4.x * w1.x + c4.y * w1.y + c4.z * w1.z + c4.w * w1.w
            + m4.x * w2.x + m4.y * w2.y + m4.z * w2.z + m4.w * w2.w;
#pragma unroll
    for (int off = 32; off; off >>= 1) p += __shfl_xor(p, off);
    if (lane == 0) pg[row] = 1.0f / (1.0f + __expf(-(p + b_gen[0])));
}

// ---------------- vocab GEMM pass 1: Z[row] += sum(exp(logit)) — NO logit store --------
__global__ __launch_bounds__(256) void gemm_vocab_z(
    const unsigned short* __restrict__ A,   // [1024][256] bf16
    const unsigned short* __restrict__ Bt,  // [32000][256] bf16
    const float* __restrict__ b_state,
    float* __restrict__ Z)
{
    __shared__ short Al[128][64];   // 16 KB
    __shared__ short Bl[128][64];   // 16 KB
    __shared__ float bst[128];

    const int tid = threadIdx.x;
    const int swz = (blockIdx.x & 7) * 250 + (blockIdx.x >> 3);  // bijective XCD swizzle
    const int m0 = (swz & 7) * 128;     // m-major: consecutive swz share Wt n-tile
    const int n0 = (swz >> 3) * 128;

    if (tid < 128) bst[tid] = b_state[n0 + tid];

    const int wid = tid >> 6, lane = tid & 63;
    const int wm = wid & 1, wn = wid >> 1;
    const int quad = lane >> 4, l15 = lane & 15;
    const int srow = lane >> 3;                        // row within 8-row chunk (=r&7)
    const int scolz = ((lane & 7) ^ srow) << 3;        // pre-swizzled source column

    f32x4 acc[4][4];
#pragma unroll
    for (int i = 0; i < 4; i++)
#pragma unroll
        for (int j = 0; j < 4; j++) acc[i][j] = f32x4{0.f, 0.f, 0.f, 0.f};

    for (int k0 = 0; k0 < D_; k0 += 64) {
        __syncthreads();
#pragma unroll
        for (int j = 0; j < 4; j++) {
            const int c = j * 4 + wid;
            const int r = c * 8 + srow;
            gload_lds16(&A[(size_t)(m0 + r) * D_ + k0 + scolz], &Al[c * 8][0]);
        }
#pragma unroll
        for (int j = 0; j < 4; j++) {
            const int c = j * 4 + wid;
            const int r = c * 8 + srow;
            gload_lds16(&Bt[(size_t)(n0 + r) * D_ + k0 + scolz], &Bl[c * 8][0]);
        }
        __syncthreads();
#pragma unroll
        for (int ks = 0; ks < 64; ks += 32) {
            short8 af[4], bf[4];
#pragma unroll
            for (int mt = 0; mt < 4; mt++) {
                const int row = wm * 64 + mt * 16 + l15;
                af[mt] = *(const short8*)&Al[row][(ks + quad * 8) ^ ((l15 & 7) << 3)];
            }
#pragma unroll
            for (int nt = 0; nt < 4; nt++) {
                const int row = wn * 64 + nt * 16 + l15;
                bf[nt] = *(const short8*)&Bl[row][(ks + quad * 8) ^ ((l15 & 7) << 3)];
            }
#pragma unroll
            for (int mt = 0; mt < 4; mt++)
#pragma unroll
                for (int nt = 0; nt < 4; nt++)
                    acc[mt][nt] = __builtin_amdgcn_mfma_f32_16x16x32_bf16(
                        af[mt], bf[nt], acc[mt][nt], 0, 0, 0);
        }
    }

#pragma unroll
    for (int mt = 0; mt < 4; mt++) {
        float rs[4] = {0.f, 0.f, 0.f, 0.f};
#pragma unroll
        for (int nt = 0; nt < 4; nt++) {
            const float bcol = bst[wn * 64 + nt * 16 + l15];
#pragma unroll
            for (int r = 0; r < 4; r++)
                rs[r] += __expf(acc[mt][nt][r] + bcol);
        }
#pragma unroll
        for (int r = 0; r < 4; r++) {
            float v = rs[r];
            v += __shfl_xor(v, 1);
            v += __shfl_xor(v, 2);
            v += __shfl_xor(v, 4);
            v += __shfl_xor(v, 8);
            if (l15 == 0)
                atomicAdd(&Z[m0 + wm * 64 + mt * 16 + quad * 4 + r], v);
        }
    }
}

// ---------------- vocab GEMM pass 2 + fused sparse fixup (acc static-indexed) ----------
// out = logit + bias + log(pg)-log(Z). Fixup targets owned per block; after the plain
// stores, owning lanes recompute from live acc and re-store. Rule #20: the fixup
// column's nt is matched via a static #pragma unroll + guard so every acc[mt][nt][r]
// index is compile-time (R8's runtime-nt demoted acc to scratch: WRITE 716 MB, 191 µs).
__global__ __launch_bounds__(256) void gemm_vocab_out(
    const unsigned short* __restrict__ A,   // [1024][256] bf16
    const unsigned short* __restrict__ Bt,  // [32000][256] bf16
    const float* __restrict__ b_state,
    const float* __restrict__ pg,
    const float* __restrict__ Z,
    const int* __restrict__ cp,
    const int* __restrict__ nexta,
    const int* __restrict__ leader,
    const float* __restrict__ S,            // attn probs [1024][512]
    float* __restrict__ out)
{
    __shared__ short Al[128][64];   // 16 KB
    __shared__ short Bl[128][64];   // 16 KB
    __shared__ float bst[128];
    __shared__ float rcs[128];
    __shared__ int mlist[256];      // packed matches: (h<<16)|(k<<7)|col_local
    __shared__ int nm_sh;

    const int tid = threadIdx.x;
    const int swz = (blockIdx.x & 7) * 250 + (blockIdx.x >> 3);  // bijective XCD swizzle
    const int m0 = (swz & 7) * 128;
    const int n0 = (swz >> 3) * 128;

    if (tid < 128) {
        bst[tid] = b_state[n0 + tid];
        rcs[tid] = logf(pg[m0 + tid]) - logf(Z[m0 + tid]);
    }
    if (tid == 0) nm_sh = 0;
    __syncthreads();
    // scan leaders of the block's 2 batches for values in this n-range
#pragma unroll
    for (int h = 0; h < 2; h++) {
        const int b = (m0 >> 6) + h;
        for (int k = tid; k < TK_; k += 256) {
            if (leader[b * TK_ + k]) {
                const int v = cp[b * TK_ + k];
                if (v >= n0 && v < n0 + 128) {
                    const int e = atomicAdd(&nm_sh, 1);
                    if (e < 256) mlist[e] = (h << 16) | (k << 7) | (v - n0);
                }
            }
        }
    }
    // (k-loop barriers below make mlist/nm_sh visible before the epilogue)

    const int wid = tid >> 6, lane = tid & 63;
    const int wm = wid & 1, wn = wid >> 1;
    const int quad = lane >> 4, l15 = lane & 15;
    const int srow = lane >> 3;
    const int scolz = ((lane & 7) ^ srow) << 3;        // pre-swizzled source column

    f32x4 acc[4][4];
#pragma unroll
    for (int i = 0; i < 4; i++)
#pragma unroll
        for (int j = 0; j < 4; j++) acc[i][j] = f32x4{0.f, 0.f, 0.f, 0.f};

    for (int k0 = 0; k0 < D_; k0 += 64) {
        __syncthreads();
#pragma unroll
        for (int j = 0; j < 4; j++) {
            const int c = j * 4 + wid;
            const int r = c * 8 + srow;
            gload_lds16(&A[(size_t)(m0 + r) * D_ + k0 + scolz], &Al[c * 8][0]);
        }
#pragma unroll
        for (int j = 0; j < 4; j++) {
            const int c = j * 4 + wid;
            const int r = c * 8 + srow;
            gload_lds16(&Bt[(size_t)(n0 + r) * D_ + k0 + scolz], &Bl[c * 8][0]);
        }
        __syncthreads();
#pragma unroll
        for (int ks = 0; ks < 64; ks += 32) {
            short8 af[4], bf[4];
#pragma unroll
            for (int mt = 0; mt < 4; mt++) {
                const int row = wm * 64 + mt * 16 + l15;
                af[mt] = *(const short8*)&Al[row][(ks + quad * 8) ^ ((l15 & 7) << 3)];
            }
#pragma unroll
            for (int nt = 0; nt < 4; nt++) {
                const int row = wn * 64 + nt * 16 + l15;
                bf[nt] = *(const short8*)&Bl[row][(ks + quad * 8) ^ ((l15 & 7) << 3)];
            }
#pragma unroll
            for (int mt = 0; mt < 4; mt++)
#pragma unroll
                for (int nt = 0; nt < 4; nt++)
                    acc[mt][nt] = __builtin_amdgcn_mfma_f32_16x16x32_bf16(
                        af[mt], bf[nt], acc[mt][nt], 0, 0, 0);
        }
    }

    // plain stores (branch-free hot path)
#pragma unroll
    for (int mt = 0; mt < 4; mt++) {
#pragma unroll
        for (int nt = 0; nt < 4; nt++) {
            const float bcol = bst[wn * 64 + nt * 16 + l15];
#pragma unroll
            for (int r = 0; r < 4; r++) {
                const int row = wm * 64 + mt * 16 + quad * 4 + r;
                const int col = wn * 64 + nt * 16 + l15;
                out[(size_t)(m0 + row) * V_ + n0 + col] = acc[mt][nt][r] + bcol + rcs[row];
            }
        }
    }

    // sparse fixup: re-store corrected values for matched columns (rare).
    // nt matched STATICALLY (rule #20) so acc indices are compile-time.
    const int nm = (nm_sh < 256) ? nm_sh : 256;
    for (int e = 0; e < nm; e++) {
        const int pk = mlist[e];
        const int cl = pk & 127;            // col local 0..127
        const int h  = (pk >> 16) & 1;      // batch half = required wm
        if ((cl >> 6) == wn && (cl & 15) == l15 && h == wm) {
            const int ntv = (cl >> 4) & 3;
            const int k  = (pk >> 7) & 511;
            const int b  = (m0 >> 6) + h;
            // chain sum once per (lane, match): identical order to old fixup_kernel
#pragma unroll
            for (int nt = 0; nt < 4; nt++) {
                if (nt != ntv) continue;
#pragma unroll
                for (int mt = 0; mt < 4; mt++)
#pragma unroll
                    for (int r = 0; r < 4; r++) {
                        const int row = wm * 64 + mt * 16 + quad * 4 + r;
                        const int rr = m0 + row;
                        float a = S[(size_t)rr * TK_ + k];
                        int j = nexta[b * TK_ + k];
                        while (j >= 0) { a += S[(size_t)rr * TK_ + j]; j = nexta[b * TK_ + j]; }
                        const float v0 = acc[mt][nt][r] + bst[cl] + rcs[row];
                        out[(size_t)rr * V_ + n0 + cl] =
                            logf(expf(v0) + (1.0f - pg[rr]) * a);
                    }
            }
        }
    }
}

extern "C" void kernel_launch(void* const* d_in, const int* in_sizes, int n_in,
                              void* d_out, int out_size, void* d_ws, size_t ws_size,
                              hipStream_t stream)
{
    const float* domainslots = (const float*)d_in[0];
    const float* out_states  = (const float*)d_in[1];
    const float* context     = (const float*)d_in[2];
    const int*   cp          = (const int*)d_in[3];
    const float* W_state     = (const float*)d_in[4];
    const float* b_state     = (const float*)d_in[5];
    const float* W_gen       = (const float*)d_in[6];
    const float* b_gen       = (const float*)d_in[7];
    float* out = (float*)d_out;
    char* ws = (char*)d_ws;

    // workspace layout (bytes)
    float* Z      = (float*)(ws);                          //  4 KB
    float* pg     = (float*)(ws + 4096);                   //  4 KB
    float* S      = (float*)(ws + 12288);                  //  2 MB (scores -> attn in place)
    int* nexta    = (int*)(ws + 2109440);                  // 32 KB
    int* leader   = (int*)(ws + 2142208);                  // 32 KB
    unsigned short* Ab = (unsigned short*)(ws + 2174976);  // 512 KB
    unsigned short* Wt = (unsigned short*)(ws + 2699264);  // 16 MB -> ends 19083264
    unsigned short* Cb = (unsigned short*)(ws + 19083264); // 4 MB
    unsigned short* Ct = (unsigned short*)(ws + 23277568); // 4 MB
    unsigned short* Pb = (unsigned short*)(ws + 27471872); // 1 MB
    float* cv     = (float*)(ws + 28520448);               // 1 MB -> ends ~29.6 MB

    // L1: fused prep (dedup + conv_w + conv_c + conv_a + zero-Z)
    prep_kernel<<<2785, 256, 0, stream>>>(W_state, Wt, context, Cb, Ct,
                                          out_states, Ab, cp, nexta, leader, Z);

    // L2: QK — S = Ab @ Cb^T / 16 : per batch M=64,N=512,K=256
    gemm_small<D_, D_, D_><<<B_ * 4, 256, 0, stream>>>(Ab, Cb, S, TK_, 4, TK_, 0.0625f);

    // L3: softmax
    softmax_kernel<<<M_ / 4, 256, 0, stream>>>(S, Pb);

    // L4: PV — cv = P @ C : per batch M=64,N=256,K=512 (Bt = Ct)
    gemm_small<TK_, TK_, TK_><<<B_ * 2, 256, 0, stream>>>(Pb, Ct, cv, D_, 2, D_, 1.0f);

    // L5: pgen
    pgen_kernel<<<M_ / 4, 256, 0, stream>>>(out_states, cv, domainslots, W_gen, b_gen, pg);

    // L6: vocab pass 1 — Z only
    gemm_vocab_z<<<(M_ / 128) * (V_ / 128), 256, 0, stream>>>(Ab, Wt, b_state, Z);

    // L7: vocab pass 2 + fused fixup — final out
    gemm_vocab_out<<<(M_ / 128) * (V_ / 128), 256, 0, stream>>>(
        Ab, Wt, b_state, pg, Z, cp, nexta, leader, S, out);
}

// Round 10
// 298.371 us; speedup vs baseline: 1.3946x; 1.1573x over previous
//
#include <hip/hip_runtime.h>
#include <math.h>

typedef short short8 __attribute__((ext_vector_type(8)));
typedef float f32x4 __attribute__((ext_vector_type(4)));

#define B_ 16
#define TQ_ 64
#define TK_ 512
#define D_ 256
#define V_ 32000
#define M_ (B_ * TQ_)   // 1024 rows

__device__ __forceinline__ unsigned short f2bf(float x) {
    unsigned int u = __float_as_uint(x);
    unsigned int r = (u + 0x7fffu + ((u >> 16) & 1u)) >> 16;
    return (unsigned short)r;
}

__device__ __forceinline__ void gload_lds16(const void* g, void* l) {
    __builtin_amdgcn_global_load_lds(
        (const __attribute__((address_space(1))) void*)g,
        (__attribute__((address_space(3))) void*)l, 16, 0, 0);
}

// ---------------- fused prep: dedup | conv_w | conv_c | conv_a | zero-Z ----------------
__global__ __launch_bounds__(256) void prep_kernel(
    const float* __restrict__ W, unsigned short* __restrict__ Wt,
    const float* __restrict__ ctx, unsigned short* __restrict__ Cb,
    unsigned short* __restrict__ Ct,
    const float* __restrict__ A, unsigned short* __restrict__ Ab,
    const int* __restrict__ cp, int* __restrict__ nexta, int* __restrict__ leader,
    float* __restrict__ Z)
{
    __shared__ float tile[64][65];
    __shared__ __align__(16) int c[TK_];
    const int bid = blockIdx.x;
    const int tid = threadIdx.x;

    if (bid < 16) {                         // ---- dedup ----
        const int b = bid;
        c[tid] = cp[b * TK_ + tid];
        c[tid + 256] = cp[b * TK_ + 256 + tid];
        __syncthreads();
        for (int k = tid; k < TK_; k += 256) {
            const int v = c[k];
            int fm = 1024, nx = 1024;
#pragma unroll 8
            for (int j0 = 0; j0 < TK_; j0 += 4) {
                const int4 q = *(const int4*)&c[j0];
                if (q.x == v) { fm = min(fm, j0);     if (j0     > k) nx = min(nx, j0);     }
                if (q.y == v) { fm = min(fm, j0 + 1); if (j0 + 1 > k) nx = min(nx, j0 + 1); }
                if (q.z == v) { fm = min(fm, j0 + 2); if (j0 + 2 > k) nx = min(nx, j0 + 2); }
                if (q.w == v) { fm = min(fm, j0 + 3); if (j0 + 3 > k) nx = min(nx, j0 + 3); }
            }
            nexta[b * TK_ + k] = (nx < 1024) ? nx : -1;
            leader[b * TK_ + k] = (fm == k) ? 1 : 0;
        }
    } else if (bid < 2016) {                // ---- conv_w ----
        const int wb = bid - 16;
        const int k0 = (wb & 3) * 64;
        const int n0 = (wb >> 2) * 64;
#pragma unroll
        for (int i = 0; i < 16; i++) {
            const int r = i * 4 + (tid >> 6), cc = tid & 63;
            tile[r][cc] = W[(k0 + r) * V_ + n0 + cc];
        }
        __syncthreads();
#pragma unroll
        for (int i = 0; i < 4; i++) {
            const int nl = i * 16 + (tid >> 4);
            const int kq = (tid & 15) * 4;
            ushort4 o;
            o.x = f2bf(tile[kq + 0][nl]);
            o.y = f2bf(tile[kq + 1][nl]);
            o.z = f2bf(tile[kq + 2][nl]);
            o.w = f2bf(tile[kq + 3][nl]);
            *(ushort4*)&Wt[(n0 + nl) * D_ + k0 + kq] = o;
        }
    } else if (bid < 2528) {                // ---- conv_c ----
        const int cbid = bid - 2016;
        const int b = cbid >> 5;
        const int r5 = cbid & 31;
        const int k0 = (r5 >> 2) * 64;
        const int d0 = (r5 & 3) * 64;
#pragma unroll
        for (int i = 0; i < 16; i++) {
            const int r = i * 4 + (tid >> 6), cc = tid & 63;
            const float v = ctx[((b * TK_) + k0 + r) * D_ + d0 + cc];
            tile[r][cc] = v;
            Cb[((b * TK_) + k0 + r) * D_ + d0 + cc] = f2bf(v);
        }
        __syncthreads();
#pragma unroll
        for (int i = 0; i < 4; i++) {
            const int dl = i * 16 + (tid >> 4);
            const int kq = (tid & 15) * 4;
            ushort4 o;
            o.x = f2bf(tile[kq + 0][dl]);
            o.y = f2bf(tile[kq + 1][dl]);
            o.z = f2bf(tile[kq + 2][dl]);
            o.w = f2bf(tile[kq + 3][dl]);
            *(ushort4*)&Ct[((b * D_) + d0 + dl) * TK_ + k0 + kq] = o;
        }
    } else if (bid < 2784) {                // ---- conv_a ----
        const int i = ((bid - 2528) * 256 + tid) * 4;
        const float4 v = *(const float4*)&A[i];
        ushort4 o;
        o.x = f2bf(v.x); o.y = f2bf(v.y); o.z = f2bf(v.z); o.w = f2bf(v.w);
        *(ushort4*)&Ab[i] = o;
    } else {                                // ---- zero Z ----
        ((float4*)Z)[tid] = float4{0.f, 0.f, 0.f, 0.f};
    }
}

// ---------------- small batched GEMM: C[b] = A[b] @ Bt[b]^T (both bf16, K-contiguous) ----
template <int LDA, int LDB, int KTOT>
__global__ __launch_bounds__(256) void gemm_small(
    const unsigned short* __restrict__ A,
    const unsigned short* __restrict__ Bt,
    float* __restrict__ C, int ldc, int nchunks, int btrows, float scale)
{
    __shared__ short Al[64][72];
    __shared__ short Bl[128][72];
    const int tid = threadIdx.x;
    const int b = blockIdx.x / nchunks;
    const int n0 = (blockIdx.x % nchunks) * 128;
    A += (size_t)b * 64 * LDA;
    Bt += (size_t)b * btrows * LDB;
    C += (size_t)b * 64 * ldc;

    const int wid = tid >> 6;
    const int lane = tid & 63;
    const int wm = wid & 1, wn = wid >> 1;
    const int quad = lane >> 4, l15 = lane & 15;

    f32x4 acc[2][4];
#pragma unroll
    for (int i = 0; i < 2; i++)
#pragma unroll
        for (int j = 0; j < 4; j++) acc[i][j] = f32x4{0.f, 0.f, 0.f, 0.f};

    for (int k0 = 0; k0 < KTOT; k0 += 64) {
        __syncthreads();
#pragma unroll
        for (int i = 0; i < 2; i++) {
            const int c = tid + i * 256;
            const int r = c >> 3, kc = (c & 7) * 8;
            *(uint4*)&Al[r][kc] = *(const uint4*)&A[r * LDA + k0 + kc];
        }
#pragma unroll
        for (int i = 0; i < 4; i++) {
            const int c = tid + i * 256;
            const int r = c >> 3, kc = (c & 7) * 8;
            *(uint4*)&Bl[r][kc] = *(const uint4*)&Bt[(n0 + r) * LDB + k0 + kc];
        }
        __syncthreads();
#pragma unroll
        for (int ks = 0; ks < 64; ks += 32) {
            short8 af[2], bf[4];
#pragma unroll
            for (int mt = 0; mt < 2; mt++)
                af[mt] = *(const short8*)&Al[wm * 32 + mt * 16 + l15][ks + quad * 8];
#pragma unroll
            for (int nt = 0; nt < 4; nt++)
                bf[nt] = *(const short8*)&Bl[wn * 64 + nt * 16 + l15][ks + quad * 8];
#pragma unroll
            for (int mt = 0; mt < 2; mt++)
#pragma unroll
                for (int nt = 0; nt < 4; nt++)
                    acc[mt][nt] = __builtin_amdgcn_mfma_f32_16x16x32_bf16(
                        af[mt], bf[nt], acc[mt][nt], 0, 0, 0);
        }
    }
#pragma unroll
    for (int mt = 0; mt < 2; mt++)
#pragma unroll
        for (int nt = 0; nt < 4; nt++)
#pragma unroll
            for (int r = 0; r < 4; r++) {
                const int rl = wm * 32 + mt * 16 + quad * 4 + r;
                const int col = n0 + wn * 64 + nt * 16 + l15;
                C[rl * ldc + col] = acc[mt][nt][r] * scale;
            }
}

// ---------------- z-role body: vocab pass-1 tile (R3/R6 code, g = global z index) -------
__device__ __forceinline__ void z_body(
    int g, const unsigned short* __restrict__ A, const unsigned short* __restrict__ Bt,
    const float* __restrict__ b_state, float* __restrict__ Z, char* smem)
{
    short (*Al)[64] = (short(*)[64])smem;             // 16 KB
    short (*Bl)[64] = (short(*)[64])(smem + 16384);   // 16 KB
    float* bst = (float*)(smem + 32768);              // 512 B

    const int tid = threadIdx.x;
    const int swz = (g & 7) * 250 + (g >> 3);         // bijective XCD swizzle over 2000
    const int m0 = (swz & 7) * 128;
    const int n0 = (swz >> 3) * 128;

    if (tid < 128) bst[tid] = b_state[n0 + tid];

    const int wid = tid >> 6, lane = tid & 63;
    const int wm = wid & 1, wn = wid >> 1;
    const int quad = lane >> 4, l15 = lane & 15;
    const int srow = lane >> 3;
    const int scolz = ((lane & 7) ^ srow) << 3;       // pre-swizzled source column

    f32x4 acc[4][4];
#pragma unroll
    for (int i = 0; i < 4; i++)
#pragma unroll
        for (int j = 0; j < 4; j++) acc[i][j] = f32x4{0.f, 0.f, 0.f, 0.f};

    for (int k0 = 0; k0 < D_; k0 += 64) {
        __syncthreads();
#pragma unroll
        for (int j = 0; j < 4; j++) {
            const int c = j * 4 + wid;
            const int r = c * 8 + srow;
            gload_lds16(&A[(size_t)(m0 + r) * D_ + k0 + scolz], &Al[c * 8][0]);
        }
#pragma unroll
        for (int j = 0; j < 4; j++) {
            const int c = j * 4 + wid;
            const int r = c * 8 + srow;
            gload_lds16(&Bt[(size_t)(n0 + r) * D_ + k0 + scolz], &Bl[c * 8][0]);
        }
        __syncthreads();
#pragma unroll
        for (int ks = 0; ks < 64; ks += 32) {
            short8 af[4], bf[4];
#pragma unroll
            for (int mt = 0; mt < 4; mt++) {
                const int row = wm * 64 + mt * 16 + l15;
                af[mt] = *(const short8*)&Al[row][(ks + quad * 8) ^ ((l15 & 7) << 3)];
            }
#pragma unroll
            for (int nt = 0; nt < 4; nt++) {
                const int row = wn * 64 + nt * 16 + l15;
                bf[nt] = *(const short8*)&Bl[row][(ks + quad * 8) ^ ((l15 & 7) << 3)];
            }
#pragma unroll
            for (int mt = 0; mt < 4; mt++)
#pragma unroll
                for (int nt = 0; nt < 4; nt++)
                    acc[mt][nt] = __builtin_amdgcn_mfma_f32_16x16x32_bf16(
                        af[mt], bf[nt], acc[mt][nt], 0, 0, 0);
        }
    }

#pragma unroll
    for (int mt = 0; mt < 4; mt++) {
        float rs[4] = {0.f, 0.f, 0.f, 0.f};
#pragma unroll
        for (int nt = 0; nt < 4; nt++) {
            const float bcol = bst[wn * 64 + nt * 16 + l15];
#pragma unroll
            for (int r = 0; r < 4; r++)
                rs[r] += __expf(acc[mt][nt][r] + bcol);
        }
#pragma unroll
        for (int r = 0; r < 4; r++) {
            float v = rs[r];
            v += __shfl_xor(v, 1);
            v += __shfl_xor(v, 2);
            v += __shfl_xor(v, 4);
            v += __shfl_xor(v, 8);
            if (l15 == 0)
                atomicAdd(&Z[m0 + wm * 64 + mt * 16 + quad * 4 + r], v);
        }
    }
}

// ---------------- QK-role body: gemm_small<256,256,256> with constants inlined ----------
__device__ __forceinline__ void qk_body(
    int qb, const unsigned short* __restrict__ A, const unsigned short* __restrict__ Bt,
    float* __restrict__ C, char* smem)
{
    short (*Al)[72] = (short(*)[72])smem;                   // 64 x 72 = 9216 B
    short (*Bl)[72] = (short(*)[72])(smem + 64 * 72 * 2);   // 128 x 72 = 18432 B
    const int tid = threadIdx.x;
    const int b = qb >> 2;
    const int n0 = (qb & 3) * 128;
    A += (size_t)b * 64 * D_;
    Bt += (size_t)b * TK_ * D_;
    C += (size_t)b * 64 * TK_;

    const int wid = tid >> 6;
    const int lane = tid & 63;
    const int wm = wid & 1, wn = wid >> 1;
    const int quad = lane >> 4, l15 = lane & 15;

    f32x4 acc[2][4];
#pragma unroll
    for (int i = 0; i < 2; i++)
#pragma unroll
        for (int j = 0; j < 4; j++) acc[i][j] = f32x4{0.f, 0.f, 0.f, 0.f};

    for (int k0 = 0; k0 < D_; k0 += 64) {
        __syncthreads();
#pragma unroll
        for (int i = 0; i < 2; i++) {
            const int c = tid + i * 256;
            const int r = c >> 3, kc = (c & 7) * 8;
            *(uint4*)&Al[r][kc] = *(const uint4*)&A[r * D_ + k0 + kc];
        }
#pragma unroll
        for (int i = 0; i < 4; i++) {
            const int c = tid + i * 256;
            const int r = c >> 3, kc = (c & 7) * 8;
            *(uint4*)&Bl[r][kc] = *(const uint4*)&Bt[(n0 + r) * D_ + k0 + kc];
        }
        __syncthreads();
#pragma unroll
        for (int ks = 0; ks < 64; ks += 32) {
            short8 af[2], bf[4];
#pragma unroll
            for (int mt = 0; mt < 2; mt++)
                af[mt] = *(const short8*)&Al[wm * 32 + mt * 16 + l15][ks + quad * 8];
#pragma unroll
            for (int nt = 0; nt < 4; nt++)
                bf[nt] = *(const short8*)&Bl[wn * 64 + nt * 16 + l15][ks + quad * 8];
#pragma unroll
            for (int mt = 0; mt < 2; mt++)
#pragma unroll
                for (int nt = 0; nt < 4; nt++)
                    acc[mt][nt] = __builtin_amdgcn_mfma_f32_16x16x32_bf16(
                        af[mt], bf[nt], acc[mt][nt], 0, 0, 0);
        }
    }
#pragma unroll
    for (int mt = 0; mt < 2; mt++)
#pragma unroll
        for (int nt = 0; nt < 4; nt++)
#pragma unroll
            for (int r = 0; r < 4; r++) {
                const int rl = wm * 32 + mt * 16 + quad * 4 + r;
                const int col = n0 + wn * 64 + nt * 16 + l15;
                C[rl * TK_ + col] = acc[mt][nt][r] * 0.0625f;
            }
}

// ---------------- merged launch: z [0,2000) || QK [2000,2064) ----------------
// Both roles depend only on prep. QK's 64 blocks (~12 us serial) hide inside z's
// 2000-block shadow. ONE launch, ONE drain tail (R7's split-z had two).
__global__ __launch_bounds__(256) void zqk_kernel(
    const unsigned short* __restrict__ Ab, const unsigned short* __restrict__ Wt,
    const float* __restrict__ b_state, float* __restrict__ Z,
    const unsigned short* __restrict__ Cb, float* __restrict__ S)
{
    __shared__ __align__(16) char smem[33280];
    const int bid = blockIdx.x;
    if (bid < 2000) { z_body(bid, Ab, Wt, b_state, Z, smem); return; }
    qk_body(bid - 2000, Ab, Cb, S, smem);
}

// ---------------- softmax over S rows; write attn f32 in-place + P bf16 ----------------
__global__ __launch_bounds__(256) void softmax_kernel(
    float* __restrict__ S, unsigned short* __restrict__ Pb)
{
    const int w = threadIdx.x >> 6, lane = threadIdx.x & 63;
    const int row = blockIdx.x * 4 + w;
    float v[8], m = -1e30f;
#pragma unroll
    for (int j = 0; j < 8; j++) { v[j] = S[row * TK_ + lane + 64 * j]; m = fmaxf(m, v[j]); }
#pragma unroll
    for (int off = 32; off; off >>= 1) m = fmaxf(m, __shfl_xor(m, off));
    float s = 0.f;
#pragma unroll
    for (int j = 0; j < 8; j++) { v[j] = __expf(v[j] - m); s += v[j]; }
#pragma unroll
    for (int off = 32; off; off >>= 1) s += __shfl_xor(s, off);
    const float inv = 1.0f / s;
#pragma unroll
    for (int j = 0; j < 8; j++) {
        const float p = v[j] * inv;
        S[row * TK_ + lane + 64 * j] = p;
        Pb[row * TK_ + lane + 64 * j] = f2bf(p);
    }
}

// ---------------- p_gen: sigmoid(os.wg0 + cv.wg1 + dm.wg2 + b) per row ----------------
__global__ __launch_bounds__(256) void pgen_kernel(
    const float* __restrict__ os, const float* __restrict__ cv,
    const float* __restrict__ dm, const float* __restrict__ W_gen,
    const float* __restrict__ b_gen, float* __restrict__ pg)
{
    const int w = threadIdx.x >> 6, lane = threadIdx.x & 63;
    const int row = blockIdx.x * 4 + w;
    const int d4 = lane * 4;
    const float4 o4 = *(const float4*)&os[row * D_ + d4];
    const float4 c4 = *(const float4*)&cv[row * D_ + d4];
    const float4 m4 = *(const float4*)&dm[row * D_ + d4];
    const float4 w0 = *(const float4*)&W_gen[d4];
    const float4 w1 = *(const float4*)&W_gen[D_ + d4];
    const float4 w2 = *(const float4*)&W_gen[2 * D_ + d4];
    float p = o4.x * w0.x + o4.y * w0.y + o4.z * w0.z + o4.w * w0.w
            + c4.x * w1.x + c4.y * w1.y + c4.z * w1.z + c4.w * w1.w
            + m4.x * w2.x + m4.y * w2.y + m4.z * w2.z + m4.w * w2.w;
#pragma unroll
    for (int off = 32; off; off >>= 1) p += __shfl_xor(p, off);
    if (lane == 0) pg[row] = 1.0f / (1.0f + __expf(-(p + b_gen[0])));
}

// ---------------- vocab GEMM pass 2: recompute logits, write FINAL out once ------------
__global__ __launch_bounds__(256) void gemm_vocab_out(
    const unsigned short* __restrict__ A,   // [1024][256] bf16
    const unsigned short* __restrict__ Bt,  // [32000][256] bf16
    const float* __restrict__ b_state,
    const float* __restrict__ pg,
    const float* __restrict__ Z,
    float* __restrict__ out)
{
    __shared__ short Al[128][64];   // 16 KB
    __shared__ short Bl[128][64];   // 16 KB
    __shared__ float bst[128];
    __shared__ float rcs[128];

    const int tid = threadIdx.x;
    const int swz = (blockIdx.x & 7) * 250 + (blockIdx.x >> 3);  // bijective XCD swizzle
    const int m0 = (swz & 7) * 128;
    const int n0 = (swz >> 3) * 128;

    if (tid < 128) {
        bst[tid] = b_state[n0 + tid];
        rcs[tid] = logf(pg[m0 + tid]) - logf(Z[m0 + tid]);
    }

    const int wid = tid >> 6, lane = tid & 63;
    const int wm = wid & 1, wn = wid >> 1;
    const int quad = lane >> 4, l15 = lane & 15;
    const int srow = lane >> 3;
    const int scolz = ((lane & 7) ^ srow) << 3;        // pre-swizzled source column

    f32x4 acc[4][4];
#pragma unroll
    for (int i = 0; i < 4; i++)
#pragma unroll
        for (int j = 0; j < 4; j++) acc[i][j] = f32x4{0.f, 0.f, 0.f, 0.f};

    for (int k0 = 0; k0 < D_; k0 += 64) {
        __syncthreads();
#pragma unroll
        for (int j = 0; j < 4; j++) {
            const int c = j * 4 + wid;
            const int r = c * 8 + srow;
            gload_lds16(&A[(size_t)(m0 + r) * D_ + k0 + scolz], &Al[c * 8][0]);
        }
#pragma unroll
        for (int j = 0; j < 4; j++) {
            const int c = j * 4 + wid;
            const int r = c * 8 + srow;
            gload_lds16(&Bt[(size_t)(n0 + r) * D_ + k0 + scolz], &Bl[c * 8][0]);
        }
        __syncthreads();
#pragma unroll
        for (int ks = 0; ks < 64; ks += 32) {
            short8 af[4], bf[4];
#pragma unroll
            for (int mt = 0; mt < 4; mt++) {
                const int row = wm * 64 + mt * 16 + l15;
                af[mt] = *(const short8*)&Al[row][(ks + quad * 8) ^ ((l15 & 7) << 3)];
            }
#pragma unroll
            for (int nt = 0; nt < 4; nt++) {
                const int row = wn * 64 + nt * 16 + l15;
                bf[nt] = *(const short8*)&Bl[row][(ks + quad * 8) ^ ((l15 & 7) << 3)];
            }
#pragma unroll
            for (int mt = 0; mt < 4; mt++)
#pragma unroll
                for (int nt = 0; nt < 4; nt++)
                    acc[mt][nt] = __builtin_amdgcn_mfma_f32_16x16x32_bf16(
                        af[mt], bf[nt], acc[mt][nt], 0, 0, 0);
        }
    }

#pragma unroll
    for (int mt = 0; mt < 4; mt++) {
#pragma unroll
        for (int nt = 0; nt < 4; nt++) {
            const float bcol = bst[wn * 64 + nt * 16 + l15];
#pragma unroll
            for (int r = 0; r < 4; r++) {
                const int row = wm * 64 + mt * 16 + quad * 4 + r;
                const int col = wn * 64 + nt * 16 + l15;
                out[(size_t)(m0 + row) * V_ + n0 + col] = acc[mt][nt][r] + bcol + rcs[row];
            }
        }
    }
}

// ---------------- sparse pointer fixup ----------------
__global__ __launch_bounds__(256) void fixup_kernel(
    const int* __restrict__ cp, const int* __restrict__ nexta,
    const int* __restrict__ leader, const float* __restrict__ attn,
    const float* __restrict__ pg, float* __restrict__ out)
{
    const int t = blockIdx.x * 256 + threadIdx.x;
    const int row = t >> 9, k = t & 511;
    const int b = row >> 6;
    if (!leader[b * TK_ + k]) return;
    float a = attn[row * TK_ + k];
    int j = nexta[b * TK_ + k];
    while (j >= 0) { a += attn[row * TK_ + j]; j = nexta[b * TK_ + j]; }
    const float val = (1.0f - pg[row]) * a;
    const int v = cp[b * TK_ + k];
    const size_t idx = (size_t)row * V_ + v;
    out[idx] = logf(expf(out[idx]) + val);
}

extern "C" void kernel_launch(void* const* d_in, const int* in_sizes, int n_in,
                              void* d_out, int out_size, void* d_ws, size_t ws_size,
                              hipStream_t stream)
{
    const float* domainslots = (const float*)d_in[0];
    const float* out_states  = (const float*)d_in[1];
    const float* context     = (const float*)d_in[2];
    const int*   cp          = (const int*)d_in[3];
    const float* W_state     = (const float*)d_in[4];
    const float* b_state     = (const float*)d_in[5];
    const float* W_gen       = (const float*)d_in[6];
    const float* b_gen       = (const float*)d_in[7];
    float* out = (float*)d_out;
    char* ws = (char*)d_ws;

    // workspace layout (bytes)
    float* Z      = (float*)(ws);                          //  4 KB
    float* pg     = (float*)(ws + 4096);                   //  4 KB
    float* S      = (float*)(ws + 12288);                  //  2 MB (scores -> attn in place)
    int* nexta    = (int*)(ws + 2109440);                  // 32 KB
    int* leader   = (int*)(ws + 2142208);                  // 32 KB
    unsigned short* Ab = (unsigned short*)(ws + 2174976);  // 512 KB
    unsigned short* Wt = (unsigned short*)(ws + 2699264);  // 16 MB -> ends 19083264
    unsigned short* Cb = (unsigned short*)(ws + 19083264); // 4 MB
    unsigned short* Ct = (unsigned short*)(ws + 23277568); // 4 MB
    unsigned short* Pb = (unsigned short*)(ws + 27471872); // 1 MB
    float* cv     = (float*)(ws + 28520448);               // 1 MB -> ends ~29.6 MB

    // L1: fused prep (dedup + conv_w + conv_c + conv_a + zero-Z)
    prep_kernel<<<2785, 256, 0, stream>>>(W_state, Wt, context, Cb, Ct,
                                          out_states, Ab, cp, nexta, leader, Z);

    // L2: vocab pass 1 (z) || QK — both depend only on prep; QK hides under z
    zqk_kernel<<<2064, 256, 0, stream>>>(Ab, Wt, b_state, Z, Cb, S);

    // L3: softmax
    softmax_kernel<<<M_ / 4, 256, 0, stream>>>(S, Pb);

    // L4: PV — cv = P @ C : per batch M=64,N=256,K=512 (Bt = Ct)
    gemm_small<TK_, TK_, TK_><<<B_ * 2, 256, 0, stream>>>(Pb, Ct, cv, D_, 2, D_, 1.0f);

    // L5: pgen
    pgen_kernel<<<M_ / 4, 256, 0, stream>>>(out_states, cv, domainslots, W_gen, b_gen, pg);

    // L6: vocab pass 2 — final out = logit + bias + log(pg) - log(Z)
    gemm_vocab_out<<<(M_ / 128) * (V_ / 128), 256, 0, stream>>>(Ab, Wt, b_state, pg, Z, out);

    // L7: sparse pointer fixup
    fixup_kernel<<<(M_ * TK_) / 256, 256, 0, stream>>>(cp, nexta, leader, S, pg, out);
}